// Round 12
// baseline (263.484 us; speedup 1.0000x reference)
//
#include <hip/hip_runtime.h>

// B=8, C=256, H=W=32 -> S=1024; NH=8, DK=256; qkv dim 6144.
#define NH    8
#define DK    256
#define SS    1024
// q is pre-scaled by SCALE*log2(e) in k1 so softmax runs in exp2 domain.
#define QSCALE 0.09016844136947155f   // (1/16) * 1.4426950408889634
#define TSH   8192                    // shorts per 16 KB tile (32 rows x 256 k)

using frag8  = __attribute__((ext_vector_type(8))) short;   // 8 bf16 (4 VGPRs)
using f32x16 = __attribute__((ext_vector_type(16))) float;  // 32x32 MFMA acc

__device__ __forceinline__ unsigned short f2bf(float f) {
    unsigned int u = __float_as_uint(f);
    return (unsigned short)((u + 0x7FFFu + ((u >> 16) & 1u)) >> 16);   // RNE
}
__device__ __forceinline__ unsigned int pk2bf(float lo, float hi) {
    unsigned int ul = __float_as_uint(lo), uh = __float_as_uint(hi);
    ul += 0x7FFFu + ((ul >> 16) & 1u);
    uh += 0x7FFFu + ((uh >> 16) & 1u);
    return (ul >> 16) | (uh & 0xFFFF0000u);
}

// async global->LDS, 16B/lane; LDS dest = wave-uniform base + lane*16.
__device__ __forceinline__ void load_lds16(const void* g, void* l) {
    __builtin_amdgcn_global_load_lds(
        (const __attribute__((address_space(1))) unsigned int*)g,
        (__attribute__((address_space(3))) unsigned int*)l, 16, 0, 0);
}

// T32 format: panel = 32 rows x K cols; cell(row r, kchunk c) = 8 shorts at
// (c*32 + r)*8. A wave's MFMA fragment = 64 consecutive cells = 1 KB of
// CONTIGUOUS memory -> fragments load coalesced straight from global.
// q/k: T32 panels (rows=tokens, cols=d). v: key-permuted tiles (chunk g*2+hw,
// position j holds key 16g+4hw+(j&3)+8*(j>>2)). O (over qb): q/k T32 format.

// ---------------------------------------------------------------------------
// K0: x, Wp, Wo  fp32 -> bf16 T32 panels, one launch. (unchanged)
// ---------------------------------------------------------------------------
__global__ __launch_bounds__(256) void k0_all(
    const float* __restrict__ x,  unsigned short* __restrict__ xbT,
    const float* __restrict__ Wp, unsigned short* __restrict__ WptT,
    const float* __restrict__ Wo, unsigned short* __restrict__ WotT)
{
    __shared__ float tile[32][33];
    const int bid = blockIdx.x;
    const float* in; unsigned short* outp; int C, c0, r0; size_t pbase; int psz;
    if (bid < 2048) {            // x[8][256][1024]: k=channel(256), n=s(1024)
        int rr = bid;
        int b = rr >> 8;
        in = x + (size_t)b * 256 * 1024;
        C = 1024; c0 = (rr & 31) * 32; r0 = ((rr >> 5) & 7) * 32;
        psz = 8192; pbase = (size_t)(b * 32 + (c0 >> 5)); outp = xbT;
    } else if (bid < 3584) {     // Wp[256][6144]: k=256, n=6144
        int rr = bid - 2048;
        in = Wp; C = 6144; c0 = (rr % 192) * 32; r0 = (rr / 192) * 32;
        psz = 8192; pbase = (size_t)(c0 >> 5); outp = WptT;
    } else {                     // Wo[2048][256]: k=2048, n=256
        int rr = bid - 3584;
        in = Wo; C = 256; c0 = (rr & 7) * 32; r0 = (rr >> 3) * 32;
        psz = 65536; pbase = (size_t)(c0 >> 5); outp = WotT;
    }
    const int tx = threadIdx.x & 31, ty = threadIdx.x >> 5;
#pragma unroll
    for (int j = 0; j < 4; j++)
        tile[ty + j * 8][tx] = in[(size_t)(r0 + ty + j * 8) * C + c0 + tx];
    __syncthreads();
    const int k = r0 + tx;
    unsigned short* dst = outp + pbase * psz + ((k >> 3) * 32) * 8 + (k & 7);
#pragma unroll
    for (int j = 0; j < 4; j++)
        dst[(ty + j * 8) * 8] = f2bf(tile[tx][ty + j * 8]);
}

// ---------------------------------------------------------------------------
// K1: qkv = xt @ Wp + bp. 32x32x16 MFMA. NO LDS, NO BARRIERS: both operand
// fragments are contiguous 1 KB wave loads from T32 global. 128 dims x 128
// tokens per block, grid (48,64) -> 12 waves/SIMD oversubscription.
// Epilogues identical to r11 (verified).
// ---------------------------------------------------------------------------
__global__ __launch_bounds__(256) void k1_qkv(
    const unsigned short* __restrict__ xbT, const unsigned short* __restrict__ WptT,
    const float* __restrict__ bp,
    unsigned short* __restrict__ qb, unsigned short* __restrict__ kb,
    unsigned short* __restrict__ vb)
{
    const int t = threadIdx.x;
    const int wave = t >> 6, lane = t & 63;
    const int l32 = lane & 31, hw = lane >> 5;
    const int n0 = blockIdx.x * 128, m0 = blockIdx.y * 128;
    const int b = m0 >> 10, s0 = m0 & 1023;

    const int h = n0 / 768;
    const int rem = n0 - h * 768;
    const int tt = rem >> 8;                  // 0=q 1=k 2=v (block-uniform)
    const int dcol0 = rem & 255;

    const unsigned short* Xg = xbT + (size_t)(b * 32 + (s0 >> 5)) * TSH;
    const unsigned short* Wg = WptT + (size_t)(n0 >> 5) * TSH;

    const int fo = hw * 256 + l32 * 8;        // lane offset inside a kt-block

    // A operand = this wave's 32-row stripe; B operand = the 4 opposite panels
    const unsigned short* Ap = (tt < 2) ? (Wg + (size_t)wave * TSH)
                                        : (Xg + (size_t)wave * TSH);
    const unsigned short* Bp = (tt < 2) ? Xg : Wg;

    f32x16 acc[4];
#pragma unroll
    for (int j = 0; j < 4; j++)
#pragma unroll
        for (int r = 0; r < 16; r++) acc[j][r] = 0.f;

#pragma unroll
    for (int kt = 0; kt < 8; kt++) {
#pragma unroll
        for (int t2 = 0; t2 < 2; t2++) {
            frag8 af = *(const frag8*)(Ap + kt * 1024 + t2 * 512 + fo);
#pragma unroll
            for (int j = 0; j < 4; j++) {
                frag8 bf = *(const frag8*)(Bp + (size_t)j * TSH + kt * 1024 + t2 * 512 + fo);
                acc[j] = __builtin_amdgcn_mfma_f32_32x32x16_bf16(af, bf, acc[j], 0, 0, 0);
            }
        }
    }

    if (tt < 2) {
        // D: col l32 = token (panel j), reg r -> d-local = 4hw + (r&3) + 8*(r>>2)
        const float sc = (tt == 0) ? QSCALE : 1.0f;
        unsigned short* dst0 = (tt == 0 ? qb : kb);
        const int dc0 = (dcol0 + wave * 32) >> 3;     // base dchunk
#pragma unroll
        for (int G = 0; G < 4; G++) {
            float4 bb = *(const float4*)(&bp[n0 + wave * 32 + 4 * hw + 8 * G]);
#pragma unroll
            for (int j = 0; j < 4; j++) {
                unsigned short* cell = dst0
                    + (size_t)((b * NH + h) * 32 + (s0 >> 5) + j) * TSH
                    + ((dc0 + G) * 32 + l32) * 8 + 4 * hw;
                uint2 st;
                st.x = pk2bf((acc[j][4 * G + 0] + bb.x) * sc, (acc[j][4 * G + 1] + bb.y) * sc);
                st.y = pk2bf((acc[j][4 * G + 2] + bb.z) * sc, (acc[j][4 * G + 3] + bb.w) * sc);
                *(uint2*)cell = st;
            }
        }
    } else {
        // D: col l32 = v-dim (panel j), reg r -> key-local = 4hw + (r&3) + 8*(r>>2)
        unsigned short* vt = vb + (size_t)((b * NH + h) * 32 + (s0 >> 5) + wave) * TSH;
#pragma unroll
        for (int j = 0; j < 4; j++) {
            const int d = dcol0 + j * 32 + l32;
            const float bv = bp[n0 + j * 32 + l32];
#pragma unroll
            for (int G = 0; G < 4; G++) {
                int g = G >> 1;
                unsigned short* cell = vt + (g * 2 + hw) * 2048 + d * 8 + 4 * (G & 1);
                uint2 st;
                st.x = pk2bf(acc[j][4 * G + 0] + bv, acc[j][4 * G + 1] + bv);
                st.y = pk2bf(acc[j][4 * G + 2] + bv, acc[j][4 * G + 3] + bv);
                *(uint2*)cell = st;
            }
        }
    }
}

// ---------------------------------------------------------------------------
// K2: attention (r10/r11 verbatim — 82.5 µs stable). Dbuf LDS, unroll x2
// with compile-time buffer pointers, key-permuted V, coalesced T32 O out.
// ---------------------------------------------------------------------------
__global__ __launch_bounds__(256, 2) void k2_attn(
    const unsigned short* __restrict__ qb, const unsigned short* __restrict__ kb,
    const unsigned short* __restrict__ vb, unsigned short* __restrict__ ob)
{
    __shared__ unsigned short Ks[2][TSH];
    __shared__ unsigned short Vs[2][TSH];

    const int t = threadIdx.x;
    const int wave = t >> 6, lane = t & 63;
    const int l32 = lane & 31, hw = lane >> 5;

    const int flat = blockIdx.x;
    const int xcd = flat & 7, tt2 = flat >> 3;
    const int qt = tt2 & 7;
    const int bh = xcd * 8 + (tt2 >> 3);

    frag8 qf[16];
    {
        const unsigned short* qp = qb + ((size_t)bh * 32 + qt * 4 + wave) * TSH
                                 + hw * 256 + l32 * 8;
#pragma unroll
        for (int s = 0; s < 16; s++) qf[s] = *(const frag8*)(qp + s * 512);
    }

    f32x16 acc[8];
#pragma unroll
    for (int nb = 0; nb < 8; nb++)
#pragma unroll
        for (int r = 0; r < 16; r++) acc[nb][r] = 0.f;
    float lsum = 0.f;

    const unsigned short* kstg = kb + (size_t)bh * 32 * TSH + wave * 2048 + lane * 8;
    const unsigned short* vstg = vb + (size_t)bh * 32 * TSH + wave * 2048 + lane * 8;

    auto prefetch = [&](int buf, int kt) {
#pragma unroll
        for (int j = 0; j < 4; j++) {
            load_lds16(kstg + (size_t)kt * TSH + j * 512, &Ks[buf][wave * 2048 + j * 512]);
            load_lds16(vstg + (size_t)kt * TSH + j * 512, &Vs[buf][wave * 2048 + j * 512]);
        }
    };

    auto body = [&](const unsigned short* Kb, const unsigned short* Vb) {
        f32x16 sa0, sa1;
#pragma unroll
        for (int r = 0; r < 16; r++) { sa0[r] = 0.f; sa1[r] = 0.f; }
#pragma unroll
        for (int s = 0; s < 16; s += 2) {
            frag8 kf0 = *(const frag8*)(Kb + (2 * s + hw) * 256 + l32 * 8);
            frag8 kf1 = *(const frag8*)(Kb + (2 * s + 2 + hw) * 256 + l32 * 8);
            sa0 = __builtin_amdgcn_mfma_f32_32x32x16_bf16(kf0, qf[s], sa0, 0, 0, 0);
            sa1 = __builtin_amdgcn_mfma_f32_32x32x16_bf16(kf1, qf[s + 1], sa1, 0, 0, 0);
        }
        float p[16];
#pragma unroll
        for (int e = 0; e < 16; e++) {
            p[e] = exp2f(sa0[e] + sa1[e]);
            lsum += p[e];
        }
        frag8 pf[2];
#pragma unroll
        for (int g = 0; g < 2; g++) {
            uint4 w;
            w.x = pk2bf(p[g * 8 + 0], p[g * 8 + 1]);
            w.y = pk2bf(p[g * 8 + 2], p[g * 8 + 3]);
            w.z = pk2bf(p[g * 8 + 4], p[g * 8 + 5]);
            w.w = pk2bf(p[g * 8 + 6], p[g * 8 + 7]);
            pf[g] = *(frag8*)&w;
        }
#pragma unroll
        for (int g = 0; g < 2; g++)
#pragma unroll
            for (int nb = 0; nb < 8; nb++) {
                frag8 vf = *(const frag8*)(Vb + (g * 2 + hw) * 2048 + (nb * 32 + l32) * 8);
                acc[nb] = __builtin_amdgcn_mfma_f32_32x32x16_bf16(vf, pf[g], acc[nb], 0, 0, 0);
            }
    };

    prefetch(0, 0);
    __syncthreads();
    for (int kt = 0; kt < 30; kt += 2) {
        prefetch(1, kt + 1);
        body(&Ks[0][0], &Vs[0][0]);
        __syncthreads();
        prefetch(0, kt + 2);
        body(&Ks[1][0], &Vs[1][0]);
        __syncthreads();
    }
    prefetch(1, 31);
    body(&Ks[0][0], &Vs[0][0]);
    __syncthreads();
    body(&Ks[1][0], &Vs[1][0]);

    lsum += __shfl_xor(lsum, 32);
    const float li = 1.f / lsum;          // col l32 = q-row = this lane's row

    unsigned short* opan = ob + ((size_t)bh * 32 + qt * 4 + wave) * TSH;
#pragma unroll
    for (int nb = 0; nb < 8; nb++)
#pragma unroll
        for (int G = 0; G < 4; G++) {
            unsigned short* cell = opan + ((nb * 4 + G) * 32 + l32) * 8 + 4 * hw;
            uint2 st;
            st.x = pk2bf(acc[nb][4 * G + 0] * li, acc[nb][4 * G + 1] * li);
            st.y = pk2bf(acc[nb][4 * G + 2] * li, acc[nb][4 * G + 3] * li);
            *(uint2*)cell = st;
        }
}

// ---------------------------------------------------------------------------
// K3: out = O @ Wo + bo + xt. NO LDS, NO BARRIERS: fragments direct from T32
// global (WotT L2-hot, O from k2). Wave = 32ch x 32tok; grid (8,64).
// ---------------------------------------------------------------------------
__global__ __launch_bounds__(256) void k3_proj(
    const unsigned short* __restrict__ Ob, const unsigned short* __restrict__ WotT,
    const float* __restrict__ bo, const float* __restrict__ x,
    float* __restrict__ out)
{
    const int t = threadIdx.x;
    const int wave = t >> 6, lane = t & 63;
    const int l32 = lane & 31, hw = lane >> 5;
    const int c0 = blockIdx.x * 32;                  // channel stripe
    const int m = blockIdx.y * 128 + wave * 32;      // global token base
    const int b = m >> 10, s0 = m & 1023;

    const unsigned short* Ap = WotT + (size_t)(c0 >> 5) * 65536;
    const int fo = hw * 256 + l32 * 8;

    f32x16 acc;
#pragma unroll
    for (int r = 0; r < 16; r++) acc[r] = 0.f;

#pragma unroll 4
    for (int kt = 0; kt < 64; kt++) {                // BK=32 per step
        const int hh = kt >> 3, kc = kt & 7;
        const unsigned short* Bp = Ob + (size_t)((b * NH + hh) * 32 + (s0 >> 5)) * TSH
                                 + kc * 1024;
#pragma unroll
        for (int t2 = 0; t2 < 2; t2++) {
            frag8 af = *(const frag8*)(Ap + kt * 1024 + t2 * 512 + fo);
            frag8 bf = *(const frag8*)(Bp + t2 * 512 + fo);
            acc = __builtin_amdgcn_mfma_f32_32x32x16_bf16(af, bf, acc, 0, 0, 0);
        }
    }

    // D: col l32 = token, reg r -> ch-local = 4hw + (r&3) + 8*(r>>2)
    const int s = s0 + l32;
#pragma unroll
    for (int G = 0; G < 4; G++) {
        float4 bb = *(const float4*)(&bo[c0 + 4 * hw + 8 * G]);
#pragma unroll
        for (int e = 0; e < 4; e++) {
            const int ch = c0 + 4 * hw + 8 * G + e;
            const float bbe = (e == 0) ? bb.x : (e == 1) ? bb.y : (e == 2) ? bb.z : bb.w;
            size_t off = (size_t)(b * 256 + ch) * 1024 + s;
            out[off] = acc[4 * G + e] + bbe + x[off];
        }
    }
}

// ---------------------------------------------------------------------------
extern "C" void kernel_launch(void* const* d_in, const int* in_sizes, int n_in,
                              void* d_out, int out_size, void* d_ws, size_t ws_size,
                              hipStream_t stream)
{
    const float* x  = (const float*)d_in[0];
    const float* Wp = (const float*)d_in[1];
    const float* bp = (const float*)d_in[2];
    const float* Wo = (const float*)d_in[3];
    const float* bo = (const float*)d_in[4];
    float* out = (float*)d_out;

    char* ws = (char*)d_ws;
    unsigned short* qb   = (unsigned short*)(ws);                // T32; O overwrites
    unsigned short* kb   = (unsigned short*)(ws + 33554432);     // T32
    unsigned short* vb   = (unsigned short*)(ws + 67108864);     // key-permuted tiles
    unsigned short* xbT  = (unsigned short*)(ws + 100663296);    // T32 panels
    unsigned short* WptT = (unsigned short*)(ws + 104857600);    // T32 192 panels
    unsigned short* WotT = (unsigned short*)(ws + 108003328);    // T32 8 panels (K=2048)

    k0_all<<<dim3(4096), 256, 0, stream>>>(x, xbT, Wp, WptT, Wo, WotT);
    k1_qkv<<<dim3(48, 64), 256, 0, stream>>>(xbT, WptT, bp, qb, kb, vb);
    k2_attn<<<dim3(512), 256, 0, stream>>>(qb, kb, vb, qb /* O over Q */);
    k3_proj<<<dim3(8, 64), 256, 0, stream>>>(qb, WotT, bo, x, out);
}

// Round 13
// 217.698 us; speedup vs baseline: 1.2103x; 1.2103x over previous
//
#include <hip/hip_runtime.h>

// B=8, C=256, H=W=32 -> S=1024; NH=8, DK=256; qkv dim 6144.
#define NH    8
#define DK    256
#define SS    1024
// q is pre-scaled by SCALE*log2(e) in k1 so softmax runs in exp2 domain.
#define QSCALE 0.09016844136947155f   // (1/16) * 1.4426950408889634
#define TSH   8192                    // shorts per 16 KB tile (32 rows x 256)

using frag8  = __attribute__((ext_vector_type(8))) short;   // 8 bf16 (4 VGPRs)
using f32x4  = __attribute__((ext_vector_type(4))) float;   // 16x16 MFMA acc
using f32x16 = __attribute__((ext_vector_type(16))) float;  // 32x32 MFMA acc

__device__ __forceinline__ unsigned short f2bf(float f) {
    unsigned int u = __float_as_uint(f);
    return (unsigned short)((u + 0x7FFFu + ((u >> 16) & 1u)) >> 16);   // RNE
}
// pack two floats -> two bf16 in one uint (lo, hi), RNE
__device__ __forceinline__ unsigned int pk2bf(float lo, float hi) {
    unsigned int ul = __float_as_uint(lo), uh = __float_as_uint(hi);
    ul += 0x7FFFu + ((ul >> 16) & 1u);
    uh += 0x7FFFu + ((uh >> 16) & 1u);
    return (ul >> 16) | (uh & 0xFFFF0000u);
}

// async global->LDS, 16B per lane; LDS dest = wave-uniform base + lane*16.
__device__ __forceinline__ void load_lds16(const void* g, void* l) {
    __builtin_amdgcn_global_load_lds(
        (const __attribute__((address_space(1))) unsigned int*)g,
        (__attribute__((address_space(3))) unsigned int*)l, 16, 0, 0);
}

// Tiled layouts (shorts); k2 staging is a contiguous 16 KB copy per tile.
//  q/k: (bh*32 + s/32)*TSH + (d/8)*256 + (s%32)*8 + d%8
//  v  : key rows PERMUTED to match score-register order of lane (l32,hw):
//       chunk (g*2+hw) position j holds key = 16g + 4hw + (j&3) + 8*(j>>2)

// ---------------------------------------------------------------------------
// K0: all three transposes (x, Wp, Wo) fp32->bf16 in ONE launch. (r8 verbatim)
// ---------------------------------------------------------------------------
__global__ __launch_bounds__(256) void k0_all(
    const float* __restrict__ x,  unsigned short* __restrict__ xb,
    const float* __restrict__ Wp, unsigned short* __restrict__ Wpt,
    const float* __restrict__ Wo, unsigned short* __restrict__ Wot)
{
    __shared__ float tile[32][33];
    const int bid = blockIdx.x;
    const float* in; unsigned short* out; int R, C, c0, r0;
    if (bid < 2048) {            // x: [8][256][1024] -> [8][1024][256]
        int rr = bid;
        in = x + (size_t)(rr >> 8) * 256 * 1024;
        out = xb + (size_t)(rr >> 8) * 256 * 1024;
        R = 256; C = 1024; c0 = (rr & 31) * 32; r0 = ((rr >> 5) & 7) * 32;
    } else if (bid < 3584) {     // Wp: [256][6144] -> [6144][256]
        int rr = bid - 2048;
        in = Wp; out = Wpt; R = 256; C = 6144;
        c0 = (rr % 192) * 32; r0 = (rr / 192) * 32;
    } else {                     // Wo: [2048][256] -> [256][2048]
        int rr = bid - 3584;
        in = Wo; out = Wot; R = 2048; C = 256;
        c0 = (rr & 7) * 32; r0 = (rr >> 3) * 32;
    }
    const int tx = threadIdx.x & 31, ty = threadIdx.x >> 5;
#pragma unroll
    for (int j = 0; j < 4; j++)
        tile[ty + j * 8][tx] = in[(size_t)(r0 + ty + j * 8) * C + c0 + tx];
    __syncthreads();
#pragma unroll
    for (int j = 0; j < 4; j++)
        out[(size_t)(c0 + ty + j * 8) * R + r0 + tx] = f2bf(tile[tx][ty + j * 8]);
}

// ---------------------------------------------------------------------------
// K1: qkv = xt @ Wp + bp, bf16 MFMA, double-buffered. (r8 verbatim)
// q/k blocks compute the TRANSPOSED product (A=Wpt, B=xb) -> coalesced uint2
// epilogue into the q/k tiled layout. v blocks direct orientation -> permuted v.
// ---------------------------------------------------------------------------
__global__ __launch_bounds__(256) void k1_qkv(
    const unsigned short* __restrict__ xb, const unsigned short* __restrict__ Wpt,
    const float* __restrict__ bp,
    unsigned short* __restrict__ qb, unsigned short* __restrict__ kb,
    unsigned short* __restrict__ vb)
{
    __shared__ unsigned short As[2][128 * 32];   // xb tile (rows = tokens)
    __shared__ unsigned short Bs[2][128 * 32];   // Wpt tile (rows = qkv dims)
    const int t = threadIdx.x;
    const int wave = t >> 6, lane = t & 63;
    const int quad = lane >> 4, l16 = lane & 15;
    const int n0 = blockIdx.x * 128, m0 = blockIdx.y * 128;
    const int b = m0 >> 10, s0 = m0 & 1023;
    const int mq = (wave >> 1) * 64, nq = (wave & 1) * 64;
    const int lr = lane >> 2, lc = (lane & 3) * 8;

    const int h = n0 / 768;
    const int rem = n0 - h * 768;
    const int tt = rem >> 8;                    // 0=q 1=k 2=v (block-uniform)

    const unsigned short* Ag = xb + (size_t)(b * 1024 + s0) * 256;
    const unsigned short* Bg = Wpt + (size_t)n0 * 256;

    f32x4 acc[4][4];
#pragma unroll
    for (int i = 0; i < 4; i++)
#pragma unroll
        for (int j = 0; j < 4; j++) acc[i][j] = (f32x4){0.f, 0.f, 0.f, 0.f};

#pragma unroll
    for (int j = 0; j < 2; j++) {
        int ch = wave + j * 4;
        load_lds16(Ag + (size_t)(ch * 16 + lr) * 256 + lc, &As[0][ch * 512]);
        load_lds16(Bg + (size_t)(ch * 16 + lr) * 256 + lc, &Bs[0][ch * 512]);
    }
    __syncthreads();

    for (int kt = 0; kt < 8; kt++) {
        const int cur = kt & 1;
        if (kt < 7) {
            const int k0 = (kt + 1) * 32;
#pragma unroll
            for (int j = 0; j < 2; j++) {
                int ch = wave + j * 4;
                load_lds16(Ag + (size_t)(ch * 16 + lr) * 256 + k0 + lc, &As[cur ^ 1][ch * 512]);
                load_lds16(Bg + (size_t)(ch * 16 + lr) * 256 + k0 + lc, &Bs[cur ^ 1][ch * 512]);
            }
        }
        const unsigned short* Fa = (tt < 2) ? &Bs[cur][0] : &As[cur][0];
        const unsigned short* Fb = (tt < 2) ? &As[cur][0] : &Bs[cur][0];
        frag8 af[4], bf[4];
#pragma unroll
        for (int i = 0; i < 4; i++)
            af[i] = *(const frag8*)(&Fa[(mq + i * 16 + l16) * 32 + quad * 8]);
#pragma unroll
        for (int j = 0; j < 4; j++)
            bf[j] = *(const frag8*)(&Fb[(nq + j * 16 + l16) * 32 + quad * 8]);
#pragma unroll
        for (int i = 0; i < 4; i++)
#pragma unroll
            for (int j = 0; j < 4; j++)
                acc[i][j] = __builtin_amdgcn_mfma_f32_16x16x32_bf16(af[i], bf[j], acc[i][j], 0, 0, 0);
        __syncthreads();
    }

    const int dcol0 = rem & 255;
    const size_t bh = (size_t)(b * NH + h);

    if (tt < 2) {
        const float sc = (tt == 0) ? QSCALE : 1.0f;
        unsigned short* dst = (tt == 0 ? qb : kb) + bh * 32 * TSH;
#pragma unroll
        for (int i = 0; i < 4; i++) {
            const int mloc = mq + i * 16;
            float4 b4 = *(const float4*)(&bp[n0 + mloc + quad * 4]);
            const int octet = ((dcol0 + mloc) >> 3) + (quad >> 1);
            const int drem4 = (quad & 1) * 4;
#pragma unroll
            for (int j = 0; j < 4; j++) {
                const int s = s0 + nq + j * 16 + l16;
                unsigned short* cell = dst + (size_t)(s >> 5) * TSH
                                     + octet * 256 + (s & 31) * 8 + drem4;
                uint2 st;
                st.x = pk2bf((acc[i][j][0] + b4.x) * sc, (acc[i][j][1] + b4.y) * sc);
                st.y = pk2bf((acc[i][j][2] + b4.z) * sc, (acc[i][j][3] + b4.w) * sc);
                *(uint2*)cell = st;
            }
        }
    } else {
        unsigned short* dst = vb + bh * 32 * TSH;
        const int chunk = (quad & 1) * 2048;
        const int jjb = (quad & 2) * 2;
        float bias[4];
#pragma unroll
        for (int j = 0; j < 4; j++) bias[j] = bp[n0 + nq + j * 16 + l16];
#pragma unroll
        for (int j = 0; j < 4; j++) {
            int d = dcol0 + nq + j * 16 + l16;
#pragma unroll
            for (int i = 0; i < 4; i++) {
                int g = ((mq >> 4) + i) & 1;
                size_t tile = (size_t)((s0 + mq + i * 16) >> 5) * TSH;
                uint2 st;
                st.x = pk2bf(acc[i][j][0] + bias[j], acc[i][j][1] + bias[j]);
                st.y = pk2bf(acc[i][j][2] + bias[j], acc[i][j][3] + bias[j]);
                *(uint2*)(&dst[tile + g * 4096 + chunk + d * 8 + jjb]) = st;
            }
        }
    }
}

// ---------------------------------------------------------------------------
// K2: attention — r8 structure/formats/epilogue, with the r10-verified
// unrolled K-loop (compile-time buffer pointers, peeled tail).
// ---------------------------------------------------------------------------
__global__ __launch_bounds__(256, 2) void k2_attn(
    const unsigned short* __restrict__ qb, const unsigned short* __restrict__ kb,
    const unsigned short* __restrict__ vb, unsigned short* __restrict__ ob)
{
    __shared__ unsigned short Ks[2][TSH];
    __shared__ unsigned short Vs[2][TSH];

    const int t = threadIdx.x;
    const int wave = t >> 6, lane = t & 63;
    const int l32 = lane & 31, hw = lane >> 5;

    const int flat = blockIdx.x;
    const int xcd = flat & 7, tt2 = flat >> 3;
    const int qt = tt2 & 7;
    const int bh = xcd * 8 + (tt2 >> 3);

    const int qrow0 = qt * 128 + wave * 32;

    frag8 qf[16];
    {
        const unsigned short* qp = qb + ((size_t)bh * 32 + qt * 4 + wave) * TSH
                                 + hw * 256 + l32 * 8;
#pragma unroll
        for (int s = 0; s < 16; s++) qf[s] = *(const frag8*)(qp + s * 512);
    }

    f32x16 acc[8];
#pragma unroll
    for (int nb = 0; nb < 8; nb++)
#pragma unroll
        for (int r = 0; r < 16; r++) acc[nb][r] = 0.f;
    float lsum = 0.f;

    const unsigned short* kstg = kb + (size_t)bh * 32 * TSH + wave * 2048 + lane * 8;
    const unsigned short* vstg = vb + (size_t)bh * 32 * TSH + wave * 2048 + lane * 8;

    auto prefetch = [&](int buf, int kt) {
#pragma unroll
        for (int j = 0; j < 4; j++) {
            load_lds16(kstg + (size_t)kt * TSH + j * 512, &Ks[buf][wave * 2048 + j * 512]);
            load_lds16(vstg + (size_t)kt * TSH + j * 512, &Vs[buf][wave * 2048 + j * 512]);
        }
    };

    auto body = [&](const unsigned short* Kb, const unsigned short* Vb) {
        f32x16 sa0, sa1;
#pragma unroll
        for (int r = 0; r < 16; r++) { sa0[r] = 0.f; sa1[r] = 0.f; }
#pragma unroll
        for (int s = 0; s < 16; s += 2) {
            frag8 kf0 = *(const frag8*)(Kb + (2 * s + hw) * 256 + l32 * 8);
            frag8 kf1 = *(const frag8*)(Kb + (2 * s + 2 + hw) * 256 + l32 * 8);
            sa0 = __builtin_amdgcn_mfma_f32_32x32x16_bf16(kf0, qf[s], sa0, 0, 0, 0);
            sa1 = __builtin_amdgcn_mfma_f32_32x32x16_bf16(kf1, qf[s + 1], sa1, 0, 0, 0);
        }
        float p[16];
#pragma unroll
        for (int e = 0; e < 16; e++) {
            p[e] = exp2f(sa0[e] + sa1[e]);
            lsum += p[e];
        }
        frag8 pf[2];
#pragma unroll
        for (int g = 0; g < 2; g++) {
            uint4 w;
            w.x = pk2bf(p[g * 8 + 0], p[g * 8 + 1]);
            w.y = pk2bf(p[g * 8 + 2], p[g * 8 + 3]);
            w.z = pk2bf(p[g * 8 + 4], p[g * 8 + 5]);
            w.w = pk2bf(p[g * 8 + 6], p[g * 8 + 7]);
            pf[g] = *(frag8*)&w;
        }
        // PV: A=pf, B=vf -> D[m=qrow][col=dcol] (r8 orientation)
#pragma unroll
        for (int g = 0; g < 2; g++)
#pragma unroll
            for (int nb = 0; nb < 8; nb++) {
                frag8 vf = *(const frag8*)(Vb + (g * 2 + hw) * 2048 + (nb * 32 + l32) * 8);
                acc[nb] = __builtin_amdgcn_mfma_f32_32x32x16_bf16(pf[g], vf, acc[nb], 0, 0, 0);
            }
    };

    prefetch(0, 0);
    __syncthreads();
    for (int kt = 0; kt < 30; kt += 2) {
        prefetch(1, kt + 1);
        body(&Ks[0][0], &Vs[0][0]);
        __syncthreads();
        prefetch(0, kt + 2);
        body(&Ks[1][0], &Vs[1][0]);
        __syncthreads();
    }
    prefetch(1, 31);
    body(&Ks[0][0], &Vs[0][0]);
    __syncthreads();
    body(&Ks[1][0], &Vs[1][0]);

    lsum += __shfl_xor(lsum, 32);
    const float linv = 1.f / lsum;        // lane (l32,hw) holds row l32's inverse

    unsigned short* og = ob + ((size_t)bh * SS + qrow0) * DK + l32;
#pragma unroll
    for (int r = 0; r < 16; r++) {
        const int rowl = (r & 3) + 8 * (r >> 2) + 4 * hw;
        const float li = __shfl(linv, rowl, 64);
        unsigned short* orow = og + (size_t)rowl * DK;
#pragma unroll
        for (int nb = 0; nb < 8; nb++)
            orow[nb * 32] = f2bf(acc[nb][r] * li);
    }
}

// ---------------------------------------------------------------------------
// K3: out = O @ Wo + bo + xt, bf16 MFMA, fp32 epilogue, [B,C,S]. (r8 verbatim)
// 64x64 tiles, BK=64, double-buffered. O read row-major [BH,S,DK].
// ---------------------------------------------------------------------------
__global__ __launch_bounds__(256) void k3_proj(
    const unsigned short* __restrict__ ob, const unsigned short* __restrict__ Wot,
    const float* __restrict__ bo, const float* __restrict__ x,
    float* __restrict__ out)
{
    __shared__ unsigned short As[2][2][2048];
    __shared__ unsigned short Bs[2][2][2048];
    const int t = threadIdx.x;
    const int wave = t >> 6, lane = t & 63;
    const int quad = lane >> 4, l16 = lane & 15;
    const int n0 = blockIdx.x * 64, m0 = blockIdx.y * 64;
    const int b = m0 >> 10, s0 = m0 & 1023;
    const int mq = (wave >> 1) * 32, nq = (wave & 1) * 32;
    const int lr = lane >> 2, lc = (lane & 3) * 8;

    const unsigned short* Bg = Wot + (size_t)n0 * 2048;

    f32x4 acc[2][2];
#pragma unroll
    for (int i = 0; i < 2; i++)
#pragma unroll
        for (int j = 0; j < 2; j++) acc[i][j] = (f32x4){0.f, 0.f, 0.f, 0.f};

    auto stage = [&](int buf, int kt) {
        const int k0 = kt * 64;
        const int h = k0 >> 8, d0 = k0 & 255;
        const unsigned short* Ag = ob + (size_t)((b * 8 + h) * 1024 + s0) * 256 + d0;
#pragma unroll
        for (int sl = 0; sl < 2; sl++) {
            load_lds16(Ag + (size_t)(wave * 16 + lr) * 256 + sl * 32 + lc, &As[buf][sl][wave * 512]);
            load_lds16(Bg + (size_t)(wave * 16 + lr) * 2048 + k0 + sl * 32 + lc, &Bs[buf][sl][wave * 512]);
        }
    };

    stage(0, 0);
    __syncthreads();

    for (int kt = 0; kt < 32; kt++) {
        const int cur = kt & 1;
        if (kt < 31) stage(cur ^ 1, kt + 1);
#pragma unroll
        for (int sl = 0; sl < 2; sl++) {
            frag8 af[2], bf[2];
#pragma unroll
            for (int i = 0; i < 2; i++)
                af[i] = *(const frag8*)(&As[cur][sl][(mq + i * 16 + l16) * 32 + quad * 8]);
#pragma unroll
            for (int j = 0; j < 2; j++)
                bf[j] = *(const frag8*)(&Bs[cur][sl][(nq + j * 16 + l16) * 32 + quad * 8]);
#pragma unroll
            for (int i = 0; i < 2; i++)
#pragma unroll
                for (int j = 0; j < 2; j++)
                    acc[i][j] = __builtin_amdgcn_mfma_f32_16x16x32_bf16(af[i], bf[j], acc[i][j], 0, 0, 0);
        }
        __syncthreads();
    }

#pragma unroll
    for (int j = 0; j < 2; j++) {
        int c = n0 + nq + j * 16 + l16;
        float bias = bo[c];
#pragma unroll
        for (int i = 0; i < 2; i++) {
            int s = s0 + mq + i * 16 + quad * 4;
            size_t off = (size_t)(b * 256 + c) * 1024 + s;
            float4 xv = *(const float4*)(&x[off]);
            float4 ov;
            ov.x = acc[i][j][0] + bias + xv.x;
            ov.y = acc[i][j][1] + bias + xv.y;
            ov.z = acc[i][j][2] + bias + xv.z;
            ov.w = acc[i][j][3] + bias + xv.w;
            *(float4*)(&out[off]) = ov;
        }
    }
}

// ---------------------------------------------------------------------------
extern "C" void kernel_launch(void* const* d_in, const int* in_sizes, int n_in,
                              void* d_out, int out_size, void* d_ws, size_t ws_size,
                              hipStream_t stream)
{
    const float* x  = (const float*)d_in[0];
    const float* Wp = (const float*)d_in[1];
    const float* bp = (const float*)d_in[2];
    const float* Wo = (const float*)d_in[3];
    const float* bo = (const float*)d_in[4];
    float* out = (float*)d_out;

    char* ws = (char*)d_ws;
    unsigned short* qb  = (unsigned short*)(ws);                // tiled; O overwrites row-major
    unsigned short* kb  = (unsigned short*)(ws + 33554432);     // tiled
    unsigned short* vb  = (unsigned short*)(ws + 67108864);     // tiled, key-permuted
    unsigned short* xb  = (unsigned short*)(ws + 100663296);    // [B,S,C] bf16
    unsigned short* Wpt = (unsigned short*)(ws + 104857600);    // [6144,256] bf16
    unsigned short* Wot = (unsigned short*)(ws + 108003328);    // [256,2048] bf16

    k0_all<<<dim3(4096), 256, 0, stream>>>(x, xb, Wp, Wpt, Wo, Wot);
    k1_qkv<<<dim3(48, 64), 256, 0, stream>>>(xb, Wpt, bp, qb, kb, vb);
    k2_attn<<<dim3(512), 256, 0, stream>>>(qb, kb, vb, qb /* O over Q */);
    k3_proj<<<dim3(4, 128), 256, 0, stream>>>(qb, Wot, bo, x, out);
}